// Round 2
// baseline (503.897 us; speedup 1.0000x reference)
//
#include <hip/hip_runtime.h>
#include <cstdint>
#include <cstddef>

// ---------- types & helpers ----------
typedef __bf16 bf16x8 __attribute__((ext_vector_type(8)));
typedef float  f32x4  __attribute__((ext_vector_type(4)));
typedef unsigned short u16x4 __attribute__((ext_vector_type(4)));

typedef __attribute__((address_space(1))) void* gas1_t;
typedef __attribute__((address_space(3))) void* las3_t;

__device__ __forceinline__ unsigned short f2bf(float f) {
  union { float f; unsigned u; } v; v.f = f;
  unsigned r = v.u + 0x7fffu + ((v.u >> 16) & 1u);   // RNE
  return (unsigned short)(r >> 16);
}
__device__ __forceinline__ float bf2f(unsigned short h) {
  union { unsigned u; float f; } v; v.u = ((unsigned)h) << 16;
  return v.f;
}

// ---------- problem constants ----------
constexpr int Bc = 4, Lc = 8192, Dc = 1024, NSAMP = 2048;
constexpr int ROWS = Bc * Lc;        // 32768
constexpr int NSEL = Bc * NSAMP;     // 8192
constexpr long long Y_ELEMS = (long long)ROWS * Dc;          // 33554432
constexpr long long GRAD_OFF = Y_ELEMS;                      // grad after y
constexpr long long LOSS_OFF = GRAD_OFF + (long long)Dc*Dc;  // 34603008

// ============================================================================
// 256x256 8-phase GEMM (T3+T4+T5, conflict-free fragment-ordered LDS).
// C[m][n] = sum_k A[m][k]*B[n][k], bf16 in, fp32 out.
// MODE 0: nt-store Cf = acc + bias[col]; MODE 2: Cf = acc.
//
// LDS tile layout (bf16 units): [2 buf][2 khalf][16 subtile][64 chunk][8]
//   buf stride 16384, khalf stride 8192, subtile stride 512, chunk stride 8.
//   chunk index == lane id (q*16+r16), so ds_read_b128 = base + lane*16B
//   (linear -> zero bank conflict) and global_load_lds's linear lane-write
//   matches by construction (source address carries the permutation).
// Schedule per K-tile g (4 phases), stage slots (1 half-tile = 2 loads/thread):
//   ph1: read A-a(mi0-3)+B-a | stage A(g+1)-b (nxt)
//   ph2: read A-a(mi4-7)     | stage B(g+2)-a (cur; B-a last read ph1)
//   ph3: read A-b(mi0-3)+B-b | stage A(g+2)-a (cur; A-a last read ph2)
//   ph4: read A-b(mi4-7)     | stage B(g+2)-b (cur; B-b last read ph3)
//   group end: vmcnt(6) (3 newest halves = tile g+2 still in flight; tile g+1
//   fully landed) + barrier. Never drains to 0 except once at g=nt-2.
// ============================================================================
constexpr int BM8 = 256, BN8 = 256;

__device__ __forceinline__ void stage_half(const unsigned short* __restrict__ G,
                                           unsigned short* lds_half,
                                           int row0, int K, long long kbase,
                                           int wave, int srow) {
#pragma unroll
  for (int j = 0; j < 2; ++j) {
    const int w = wave * 2 + j;   // window == subtile index, wave-uniform
    const unsigned short* src = G + (size_t)(row0 + w * 16 + srow) * K + kbase;
    __builtin_amdgcn_global_load_lds((gas1_t)(void*)src,
                                     (las3_t)(lds_half + w * 512), 16, 0, 0);
  }
}

__device__ __forceinline__ void ld4(const unsigned short* base, int l8, bf16x8* dst) {
#pragma unroll
  for (int i = 0; i < 4; ++i)
    dst[i] = *(const bf16x8*)(base + i * 512 + l8);
}

#define PH_WAIT() do {                                        \
    __builtin_amdgcn_s_barrier();                             \
    asm volatile("s_waitcnt lgkmcnt(0)" ::: "memory");        \
    __builtin_amdgcn_sched_barrier(0);                        \
  } while (0)

template<int MODE>
__global__ __launch_bounds__(512, 2)
void gemm_bt8(const unsigned short* __restrict__ A,
              const unsigned short* __restrict__ B,
              float* __restrict__ Cf,
              const float* __restrict__ bias,
              int M, int N, int K) {
  __shared__ unsigned short sA[2 * 16384];   // 64 KB
  __shared__ unsigned short sB[2 * 16384];   // 64 KB
  const int tid  = threadIdx.x;
  const int lane = tid & 63;
  const int wave = tid >> 6;          // 0..7
  const int wm = wave >> 2;           // 0..1  (M half)
  const int wn = wave & 3;            // 0..3  (N quarter)
  const int q = lane >> 4, r16 = lane & 15;
  const int l8 = lane * 8;
  const int srow = lane & 15;                 // staging source row-in-subtile
  const long long scol = (lane >> 4) * 8;     // staging source k-offset

  // T1 bijective XCD swizzle (all launches have nwg % 8 == 0)
  const int gx   = gridDim.x;
  const int nwg  = gx * gridDim.y;
  const int orig = blockIdx.y * gx + blockIdx.x;
  const int swz  = (orig & 7) * (nwg >> 3) + (orig >> 3);
  const int m0 = (swz / gx) * BM8;
  const int n0 = (swz % gx) * BN8;

  const int nt = K >> 6;   // K-tiles of 64

  f32x4 acc[8][4] = {};

  // ---- prologue: tile0 (4 halves) + B1a, A1a, B1b ----
  {
    stage_half(A, sA + 0 * 16384 + 0 * 8192, m0, K, 0,            wave, srow ? srow : srow);
    // (call again properly below — the compiler folds; keep explicit list)
  }
  stage_half(A, sA + 0,          m0, K, 0 * 64 + 0 * 32 + scol, wave, srow);
  stage_half(A, sA + 8192,       m0, K, 0 * 64 + 1 * 32 + scol, wave, srow);
  stage_half(B, sB + 0,          n0, K, 0 * 64 + 0 * 32 + scol, wave, srow);
  stage_half(B, sB + 8192,       n0, K, 0 * 64 + 1 * 32 + scol, wave, srow);
  if (nt > 1) {
    stage_half(B, sB + 16384 + 0,    n0, K, 1 * 64 + 0 * 32 + scol, wave, srow);
    stage_half(A, sA + 16384 + 0,    m0, K, 1 * 64 + 0 * 32 + scol, wave, srow);
    stage_half(B, sB + 16384 + 8192, n0, K, 1 * 64 + 1 * 32 + scol, wave, srow);
    asm volatile("s_waitcnt vmcnt(6)" ::: "memory");
  } else {
    asm volatile("s_waitcnt vmcnt(0)" ::: "memory");
  }
  __builtin_amdgcn_s_barrier();

  for (int g = 0; g < nt; ++g) {
    const int buf = (g & 1) * 16384;
    const int nbuf = 16384 - buf;
    bf16x8 af[4], bfv[4];

    // ---------- ph1: A-a(mi0-3) + B-a ----------
    ld4(sA + buf + (wm * 8 + 0) * 512, l8, af);
    ld4(sB + buf + (wn * 4)     * 512, l8, bfv);
    if (g + 1 < nt)
      stage_half(A, sA + nbuf + 8192, m0, K, (long long)(g + 1) * 64 + 32 + scol, wave, srow);
    PH_WAIT();
    __builtin_amdgcn_s_setprio(1);
#pragma unroll
    for (int i = 0; i < 4; ++i)
#pragma unroll
      for (int ni = 0; ni < 4; ++ni)
        acc[i][ni] = __builtin_amdgcn_mfma_f32_16x16x32_bf16(af[i], bfv[ni], acc[i][ni], 0, 0, 0);
    __builtin_amdgcn_s_setprio(0);
    __builtin_amdgcn_s_barrier();

    // ---------- ph2: A-a(mi4-7) ----------
    ld4(sA + buf + (wm * 8 + 4) * 512, l8, af);
    if (g + 2 < nt)
      stage_half(B, sB + buf, n0, K, (long long)(g + 2) * 64 + scol, wave, srow);
    PH_WAIT();
    __builtin_amdgcn_s_setprio(1);
#pragma unroll
    for (int i = 0; i < 4; ++i)
#pragma unroll
      for (int ni = 0; ni < 4; ++ni)
        acc[4 + i][ni] = __builtin_amdgcn_mfma_f32_16x16x32_bf16(af[i], bfv[ni], acc[4 + i][ni], 0, 0, 0);
    __builtin_amdgcn_s_setprio(0);
    __builtin_amdgcn_s_barrier();

    // ---------- ph3: A-b(mi0-3) + B-b ----------
    ld4(sA + buf + 8192 + (wm * 8 + 0) * 512, l8, af);
    ld4(sB + buf + 8192 + (wn * 4)     * 512, l8, bfv);
    if (g + 2 < nt)
      stage_half(A, sA + buf, m0, K, (long long)(g + 2) * 64 + scol, wave, srow);
    PH_WAIT();
    __builtin_amdgcn_s_setprio(1);
#pragma unroll
    for (int i = 0; i < 4; ++i)
#pragma unroll
      for (int ni = 0; ni < 4; ++ni)
        acc[i][ni] = __builtin_amdgcn_mfma_f32_16x16x32_bf16(af[i], bfv[ni], acc[i][ni], 0, 0, 0);
    __builtin_amdgcn_s_setprio(0);
    __builtin_amdgcn_s_barrier();

    // ---------- ph4: A-b(mi4-7) ----------
    ld4(sA + buf + 8192 + (wm * 8 + 4) * 512, l8, af);
    if (g + 2 < nt)
      stage_half(B, sB + buf + 8192, n0, K, (long long)(g + 2) * 64 + 32 + scol, wave, srow);
    PH_WAIT();
    __builtin_amdgcn_s_setprio(1);
#pragma unroll
    for (int i = 0; i < 4; ++i)
#pragma unroll
      for (int ni = 0; ni < 4; ++ni)
        acc[4 + i][ni] = __builtin_amdgcn_mfma_f32_16x16x32_bf16(af[i], bfv[ni], acc[4 + i][ni], 0, 0, 0);
    __builtin_amdgcn_s_setprio(0);

    // ---------- group end: counted vmcnt (never 0 until tail) ----------
    if (g + 1 < nt) {
      if (g + 2 < nt) asm volatile("s_waitcnt vmcnt(6)" ::: "memory");
      else            asm volatile("s_waitcnt vmcnt(0)" ::: "memory");
    }
    __builtin_amdgcn_s_barrier();
  }

  // ---------- epilogue ----------
  const int row0 = m0 + wm * 128 + q * 4;
  const int col0 = n0 + wn * 64 + r16;
  float bv[4] = {0.f, 0.f, 0.f, 0.f};
  if (MODE == 0) {
#pragma unroll
    for (int ni = 0; ni < 4; ++ni) bv[ni] = bias[col0 + ni * 16];
  }
#pragma unroll
  for (int mi = 0; mi < 8; ++mi) {
#pragma unroll
    for (int r = 0; r < 4; ++r) {
      const int row = row0 + mi * 16 + r;
      const size_t base = (size_t)row * N + col0;
#pragma unroll
      for (int ni = 0; ni < 4; ++ni) {
        const size_t o = base + (size_t)ni * 16;
        float v = acc[mi][ni][r];
        if (MODE == 0) __builtin_nontemporal_store(v + bv[ni], &Cf[o]);
        else           Cf[o] = v;
      }
    }
  }
}

// ---------- legacy 128x128 B^T GEMM (kept for split-K atomic MODE 3) ----------
constexpr int BM = 128, BN = 128, BK = 64;

template<int MODE>
__global__ void gemm_bt(const unsigned short* __restrict__ A,
                        const unsigned short* __restrict__ B,
                        float* __restrict__ Cf,
                        const float* __restrict__ bias,
                        int M, int N, int K, int kchunk) {
  __shared__ unsigned short sA[BM * BK];   // 16 KB
  __shared__ unsigned short sB[BN * BK];   // 16 KB
  const int tid  = threadIdx.x;
  const int lane = tid & 63;
  const int wave = tid >> 6;
  const int wm = wave >> 1, wn = wave & 1;     // 2x2 waves, each 64x64
  const int q = lane >> 4, r16 = lane & 15;

  const int gx   = gridDim.x;
  const int nwg  = gx * gridDim.y;
  const int orig = blockIdx.y * gx + blockIdx.x;
  const int swz  = (orig & 7) * (nwg >> 3) + (orig >> 3);
  const int m0 = (swz / gx) * BM;
  const int n0 = (swz % gx) * BN;
  const int kb = blockIdx.z * kchunk;

  const int lrow = lane >> 3;        // 0..7 rows within 1KB chunk
  const int lcol = (lane & 7) * 8;   // bf16 elems; 8 elems = 16B

  f32x4 acc[4][4] = {};

  for (int k0 = kb; k0 < kb + kchunk; k0 += BK) {
#pragma unroll
    for (int j = 0; j < 4; ++j) {
      const int c = wave * 4 + j;
      const int row = c * 8 + lrow;
      const unsigned short* ga = A + (size_t)(m0 + row) * K + k0 + lcol;
      __builtin_amdgcn_global_load_lds((gas1_t)(void*)ga, (las3_t)(sA + c * 512), 16, 0, 0);
      const unsigned short* gb = B + (size_t)(n0 + row) * K + k0 + lcol;
      __builtin_amdgcn_global_load_lds((gas1_t)(void*)gb, (las3_t)(sB + c * 512), 16, 0, 0);
    }
    __syncthreads();
#pragma unroll
    for (int kk = 0; kk < BK; kk += 32) {
      bf16x8 af[4], bfv[4];
#pragma unroll
      for (int mi = 0; mi < 4; ++mi)
        af[mi] = *(const bf16x8*)(sA + (size_t)(wm*64 + mi*16 + r16) * BK + kk + q*8);
#pragma unroll
      for (int ni = 0; ni < 4; ++ni)
        bfv[ni] = *(const bf16x8*)(sB + (size_t)(wn*64 + ni*16 + r16) * BK + kk + q*8);
#pragma unroll
      for (int mi = 0; mi < 4; ++mi)
#pragma unroll
        for (int ni = 0; ni < 4; ++ni)
          acc[mi][ni] = __builtin_amdgcn_mfma_f32_16x16x32_bf16(af[mi], bfv[ni], acc[mi][ni], 0, 0, 0);
    }
    __syncthreads();
  }

  const int row0 = m0 + wm*64 + q*4;
  const int col0 = n0 + wn*64 + r16;
  float bv[4] = {0.f, 0.f, 0.f, 0.f};
  if (MODE == 0) {
#pragma unroll
    for (int ni = 0; ni < 4; ++ni) bv[ni] = bias[col0 + ni*16];
  }
#pragma unroll
  for (int mi = 0; mi < 4; ++mi) {
#pragma unroll
    for (int r = 0; r < 4; ++r) {
      const int row = row0 + mi*16 + r;
      const size_t base = (size_t)row * N + col0;
#pragma unroll
      for (int ni = 0; ni < 4; ++ni) {
        const size_t o = base + (size_t)ni * 16;
        float v = acc[mi][ni][r];
        if (MODE == 0)      __builtin_nontemporal_store(v + bv[ni], &Cf[o]);
        else if (MODE == 2) Cf[o] = v;
        else                atomicAdd(&Cf[o], v);
      }
    }
  }
}

// ---------- fp32 -> bf16 bulk convert (4 elems/thread); NT==1 streams the fp32 read ----------
template<int NT>
__global__ void cvt_f32_bf16(const float* __restrict__ in, unsigned short* __restrict__ out, long long n) {
  long long i = ((long long)blockIdx.x * 256 + threadIdx.x) * 4;
  if (i >= n) return;
  f32x4 v;
  if (NT) v = __builtin_nontemporal_load((const f32x4*)(in + i));
  else    v = *(const f32x4*)(in + i);
  u16x4 o;
  o.x = f2bf(v.x); o.y = f2bf(v.y); o.z = f2bf(v.z); o.w = f2bf(v.w);
  *(u16x4*)(out + i) = o;
}

// ---------- gather sampled tokens from bf16 x: ab[blk][:] = xb[b][idx][:] ----------
__global__ void gather_rows(const unsigned short* __restrict__ xb, const int* __restrict__ idx,
                            unsigned short* __restrict__ out) {
  const int blk = blockIdx.x;            // 0..8191 = b*2048+n
  const int b = blk >> 11, n = blk & 2047;
  const int row = idx[b * NSAMP + n];
  const unsigned short* src = xb + ((size_t)b * Lc + row) * Dc;
  unsigned short* dst = out + (size_t)blk * Dc;
  const int c = threadIdx.x * 4;
  *(u16x4*)(dst + c) = *(const u16x4*)(src + c);
}

// ---------- diagonal residual: c[i] = d_ii - bf16(d_ii) ----------
__global__ void diag_resid(const float* __restrict__ dc, float* __restrict__ cvec) {
  const int i = blockIdx.x * 256 + threadIdx.x;
  if (i >= Dc) return;
  const float v = dc[(size_t)i * Dc + i];
  cvec[i] = v - bf2f(f2bf(v));
}

// ---------- fp32 transpose -> bf16 (64x64 LDS tiles): outT[c][r] = bf16(in[r][c]) ----------
__global__ void transpose_bf16(const float* __restrict__ in, unsigned short* __restrict__ outT,
                               int R, int C) {
  __shared__ float tile[64][65];
  const int r0 = blockIdx.y * 64, c0 = blockIdx.x * 64;
  const int t = threadIdx.x;
  const int c = t & 63, r4 = t >> 6;
#pragma unroll
  for (int j = 0; j < 16; ++j) {
    const int r = j * 4 + r4;
    tile[r][c] = in[(size_t)(r0 + r) * C + c0 + c];
  }
  __syncthreads();
  const int i = t >> 2, p = t & 3;
  unsigned short* dst = outT + (size_t)(c0 + i) * R + r0 + p * 16;
#pragma unroll
  for (int j = 0; j < 16; j += 4) {
    u16x4 v;
    v.x = f2bf(tile[p*16 + j + 0][i]);
    v.y = f2bf(tile[p*16 + j + 1][i]);
    v.z = f2bf(tile[p*16 + j + 2][i]);
    v.w = f2bf(tile[p*16 + j + 3][i]);
    *(u16x4*)(dst + j) = v;
  }
}

// ---------- fused xs pass: diag correction; per-row s1=Σx²,s2=Σx⁴; per-col Σx²; bf16 transpose ----------
__global__ void xs_stats_transpose(const float* __restrict__ xs, const unsigned short* __restrict__ ab,
                                   const float* __restrict__ cvec,
                                   unsigned short* __restrict__ xsT,
                                   float* __restrict__ m2sum, float* __restrict__ s1g,
                                   float* __restrict__ s2g) {
  __shared__ float tile[64][65];
  const int n0 = blockIdx.x * 64;   // sample rows (8192)
  const int i0 = blockIdx.y * 64;   // feature cols (1024)
  const int t = threadIdx.x;
  const int c = t & 63, r4 = t >> 6;
  const float ccol = cvec[i0 + c];
#pragma unroll
  for (int j = 0; j < 16; ++j) {
    const int r = j * 4 + r4;
    const size_t o = (size_t)(n0 + r) * Dc + i0 + c;
    tile[r][c] = xs[o] + bf2f(ab[o]) * ccol;   // exact-diag correction
  }
  __syncthreads();
  if (t < 64) {
    float s1 = 0.f, s2 = 0.f;
#pragma unroll
    for (int cc = 0; cc < 64; ++cc) { float v = tile[t][cc]; float v2 = v*v; s1 += v2; s2 += v2*v2; }
    atomicAdd(&s1g[n0 + t], s1);
    atomicAdd(&s2g[n0 + t], s2);
  } else if (t < 128) {
    const int col = t - 64;
    float cs = 0.f;
#pragma unroll
    for (int rr = 0; rr < 64; ++rr) { float v = tile[rr][col]; cs += v*v; }
    atomicAdd(&m2sum[i0 + col], cs);
  }
  const int i = t >> 2, p = t & 3;
  unsigned short* dst = xsT + (size_t)(i0 + i) * NSEL + n0 + p * 16;
#pragma unroll
  for (int j = 0; j < 16; j += 4) {
    u16x4 v;
    v.x = f2bf(tile[p*16 + j + 0][i]);
    v.y = f2bf(tile[p*16 + j + 1][i]);
    v.z = f2bf(tile[p*16 + j + 2][i]);
    v.w = f2bf(tile[p*16 + j + 3][i]);
    *(u16x4*)(dst + j) = v;
  }
}

// ---------- grad writeout: off-diag 0.5*G/N, diag 0.5*(m2-1) ----------
__global__ void grad_write(const float* __restrict__ G, const float* __restrict__ m2sum,
                           float* __restrict__ out) {
  const int i = blockIdx.x * 256 + threadIdx.x;   // 0..1048575
  const int r = i >> 10, c = i & 1023;
  float g = G[i] * (0.5f / (float)NSEL);
  if (r == c) g = 0.5f * (m2sum[r] * (1.0f / (float)NSEL) - 1.0f);
  __builtin_nontemporal_store(g, &out[i]);
}

// ---------- losses: corr=(Σs1²−Σs2)/denom, white=(Σs2−2Σs1+N·d)/denom ----------
__global__ void finalize_losses(const float* __restrict__ s1g, const float* __restrict__ s2g,
                                float* __restrict__ out2) {
  __shared__ double sa[256], sb[256], sc[256];
  double a = 0, b = 0, c = 0;
  for (int n = threadIdx.x; n < NSEL; n += 256) {
    double s1 = s1g[n], s2 = s2g[n];
    a += s1 * s1; b += s2; c += s1;
  }
  const int t = threadIdx.x;
  sa[t] = a; sb[t] = b; sc[t] = c;
  __syncthreads();
  for (int s = 128; s > 0; s >>= 1) {
    if (t < s) { sa[t] += sa[t+s]; sb[t] += sb[t+s]; sc[t] += sc[t+s]; }
    __syncthreads();
  }
  if (t == 0) {
    const double denom = (double)NSEL * (double)Dc * (double)Dc;
    const double cnt   = (double)NSEL * (double)Dc;
    out2[0] = (float)((sa[0] - sb[0]) / denom);
    out2[1] = (float)((sb[0] - 2.0 * sc[0] + cnt) / denom);
  }
}

extern "C" void kernel_launch(void* const* d_in, const int* in_sizes, int n_in,
                              void* d_out, int out_size, void* d_ws, size_t ws_size,
                              hipStream_t stream) {
  const float* x      = (const float*)d_in[0];
  const float* W      = (const float*)d_in[1];
  const float* bias   = (const float*)d_in[2];
  const float* decorr = (const float*)d_in[3];
  const int*   sidx   = (const int*)d_in[4];
  float* out = (float*)d_out;

  // workspace layout (bytes)
  char* w = (char*)d_ws;
  constexpr size_t SZ_XB  = (size_t)ROWS * Dc * 2;       // x bf16            64 MB
  constexpr size_t SZ_AB  = (size_t)NSEL * Dc * 2;       // gathered sel bf16 16 MB
  constexpr size_t SZ_DT  = (size_t)Dc * Dc * 2;         // decorr^T bf16      2 MB
  constexpr size_t SZ_WB  = (size_t)Dc * Dc * 2;         // W bf16             2 MB
  constexpr size_t SZ_MB  = (size_t)Dc * Dc * 2;         // M bf16             2 MB
  constexpr size_t SZ_XS  = (size_t)NSEL * Dc * 4;       // xs fp32           32 MB
  constexpr size_t SZ_XST = (size_t)Dc * NSEL * 2;       // xs^T bf16         16 MB
  constexpr size_t SZ_MF  = (size_t)Dc * Dc * 4;         // M fp32 acc         4 MB (zeroed)
  constexpr size_t SZ_GB  = (size_t)Dc * Dc * 4;         // G fp32 acc         4 MB (zeroed)
  constexpr size_t SZ_M2  = (size_t)Dc * 4;
  constexpr size_t SZ_S1  = (size_t)NSEL * 4;
  constexpr size_t SZ_S2  = (size_t)NSEL * 4;
  constexpr size_t SZ_CV  = (size_t)Dc * 4;

  size_t off = 0;
  unsigned short* xb  = (unsigned short*)(w + off); off += SZ_XB;
  unsigned short* ab  = (unsigned short*)(w + off); off += SZ_AB;
  unsigned short* dT  = (unsigned short*)(w + off); off += SZ_DT;
  unsigned short* wb  = (unsigned short*)(w + off); off += SZ_WB;
  unsigned short* mb  = (unsigned short*)(w + off); off += SZ_MB;
  float*          xsf = (float*)(w + off);          off += SZ_XS;
  unsigned short* xsT = (unsigned short*)(w + off); off += SZ_XST;
  float*          cv  = (float*)(w + off);          off += SZ_CV;
  char*           zbase = w + off;                   // zeroed region
  float*          Mf  = (float*)(w + off);          off += SZ_MF;
  float*          Gb  = (float*)(w + off);          off += SZ_GB;
  float*          m2s = (float*)(w + off);          off += SZ_M2;
  float*          s1g = (float*)(w + off);          off += SZ_S1;
  float*          s2g = (float*)(w + off);          off += SZ_S2;
  const size_t zbytes = SZ_MF + SZ_GB + SZ_M2 + SZ_S1 + SZ_S2;

  (void)hipMemsetAsync(zbase, 0, zbytes, stream);

  // prep
  cvt_f32_bf16<1><<<(int)(Y_ELEMS / 1024), 256, 0, stream>>>(x, xb, Y_ELEMS);
  cvt_f32_bf16<0><<<Dc*Dc / 1024, 256, 0, stream>>>(W, wb, (long long)Dc*Dc);
  diag_resid<<<4, 256, 0, stream>>>(decorr, cv);
  transpose_bf16<<<dim3(Dc/64, Dc/64), 256, 0, stream>>>(decorr, dT, Dc, Dc);
  gather_rows<<<NSEL, 256, 0, stream>>>(xb, sidx, ab);

  // M = W @ decorr : split-K=8 atomic fp32 (512 blocks), then cvt to bf16
  gemm_bt<3><<<dim3(Dc/BN, Dc/BM, 8), 256, 0, stream>>>(wb, dT, Mf, nullptr, Dc, Dc, Dc, Dc/8);
  cvt_f32_bf16<0><<<Dc*Dc / 1024, 256, 0, stream>>>(Mf, mb, (long long)Dc*Dc);

  // y = x @ M^T + bias (nt stores) : 256^2 8-phase
  gemm_bt8<0><<<dim3(Dc/BN8, ROWS/BM8), 512, 0, stream>>>(xb, mb, out, bias, ROWS, Dc, Dc);

  // xs = sel @ decorr^T (bf16, K=1024; diag corrected downstream) : 256^2 8-phase
  gemm_bt8<2><<<dim3(Dc/BN8, NSEL/BM8), 512, 0, stream>>>(ab, dT, xsf, nullptr, NSEL, Dc, Dc);

  // stats + correction + transpose
  xs_stats_transpose<<<dim3(NSEL/64, Dc/64), 256, 0, stream>>>(xsf, ab, cv, xsT, m2s, s1g, s2g);

  // G = xs^T xs : split-K=16 atomic (1024 blocks)
  gemm_bt<3><<<dim3(Dc/BN, Dc/BM, 16), 256, 0, stream>>>(xsT, xsT, Gb, nullptr, Dc, Dc, NSEL, NSEL/16);

  // outputs
  grad_write<<<Dc*Dc / 256, 256, 0, stream>>>(Gb, m2s, out + GRAD_OFF);
  finalize_losses<<<1, 256, 0, stream>>>(s1g, s2g, out + LOSS_OFF);
}

// Round 3
// 486.433 us; speedup vs baseline: 1.0359x; 1.0359x over previous
//
#include <hip/hip_runtime.h>
#include <cstdint>
#include <cstddef>

// ---------- types & helpers ----------
typedef __bf16 bf16x8 __attribute__((ext_vector_type(8)));
typedef float  f32x4  __attribute__((ext_vector_type(4)));
typedef unsigned short u16x4 __attribute__((ext_vector_type(4)));

typedef __attribute__((address_space(1))) void* gas1_t;
typedef __attribute__((address_space(3))) void* las3_t;

__device__ __forceinline__ unsigned short f2bf(float f) {
  union { float f; unsigned u; } v; v.f = f;
  unsigned r = v.u + 0x7fffu + ((v.u >> 16) & 1u);   // RNE
  return (unsigned short)(r >> 16);
}
__device__ __forceinline__ float bf2f(unsigned short h) {
  union { unsigned u; float f; } v; v.u = ((unsigned)h) << 16;
  return v.f;
}

// ---------- problem constants ----------
constexpr int Bc = 4, Lc = 8192, Dc = 1024, NSAMP = 2048;
constexpr int ROWS = Bc * Lc;        // 32768
constexpr int NSEL = Bc * NSAMP;     // 8192
constexpr long long Y_ELEMS = (long long)ROWS * Dc;          // 33554432
constexpr long long GRAD_OFF = Y_ELEMS;                      // grad after y
constexpr long long LOSS_OFF = GRAD_OFF + (long long)Dc*Dc;  // 34603008

// ============================================================================
// 256x256 software-pipelined 4-phase GEMM (T3+T4 counted lgkm/vmcnt + T5).
// C[m][n] = sum_k A[m][k]*B[n][k], bf16 in, fp32 out. MODE 0: nt-store +bias.
//
// LDS tile layout (bf16 units): [2 buf][2 khalf][16 subtile][64 chunk][8]
//   chunk == lane id, so ds_read_b128 = base + lane*16B (zero bank conflict,
//   verified R2: SQ_LDS_BANK_CONFLICT == 0) and global_load_lds's linear
//   lane-write matches by construction.
//
// Pipeline (read-ahead = 1 phase, reg banks afA/afB, bvA/bvB):
//   ph1: BAR | rd afB=A-a(hi)          | stage A(g+1)b | lgkm(4) | MFMA(afA,bvA)->acc[0..3]
//   ph2: BAR | rd afA=A-b(lo), bvB=B-b | stage B(g+2)a | lgkm(8) | MFMA(afB,bvA)->acc[4..7]
//   ph3: BAR | rd afB=A-b(hi)          | stage A(g+2)a | lgkm(4) | MFMA(afA,bvB)->acc[0..3]
//   ph4: vmcnt(4) BAR | rd afA,bvA from NEXT buf | stage B(g+2)b | lgkm(8) | MFMA(afB,bvB)->acc[4..7]
// vmcnt(4) ledger at ph4 entry: outstanding stages (wave-local, issue order)
//   [B(g+1)a, A(g+1)a, B(g+1)b](from g-1) + [A(g+1)b, B(g+2)a, A(g+2)a](from g)
//   -> drain to 4 retires ALL tile-(g+1) halves; next-buf reads legal.
// WAR: every overwritten LDS region's last reads complete at a counted-lgkm
//   wait that precedes the phase-entry barrier before the overwriting stage.
// ============================================================================
constexpr int BM8 = 256, BN8 = 256;

#define WAITL(N) do { asm volatile("s_waitcnt lgkmcnt(" #N ")" ::: "memory"); \
                      __builtin_amdgcn_sched_barrier(0); } while (0)
#define WAITV(N) asm volatile("s_waitcnt vmcnt(" #N ")" ::: "memory")

__device__ __forceinline__ void stage_half2(const unsigned short* src_base,
                                            unsigned short* lds_wbase,
                                            int K, long long kofs) {
#pragma unroll
  for (int j = 0; j < 2; ++j)
    __builtin_amdgcn_global_load_lds((gas1_t)(void*)(src_base + (size_t)j * 16 * K + kofs),
                                     (las3_t)(lds_wbase + j * 512), 16, 0, 0);
}

__device__ __forceinline__ void ld4(const unsigned short* base, int l8, bf16x8* dst) {
#pragma unroll
  for (int i = 0; i < 4; ++i)
    dst[i] = *(const bf16x8*)(base + i * 512 + l8);
}

__device__ __forceinline__ void mfma16(const bf16x8* af, const bf16x8* bv, f32x4 (*acc)[4]) {
  __builtin_amdgcn_s_setprio(1);
#pragma unroll
  for (int i = 0; i < 4; ++i)
#pragma unroll
    for (int n = 0; n < 4; ++n)
      acc[i][n] = __builtin_amdgcn_mfma_f32_16x16x32_bf16(af[i], bv[n], acc[i][n], 0, 0, 0);
  __builtin_amdgcn_s_setprio(0);
}

template<int MODE>
__global__ __launch_bounds__(512, 2)
void gemm_bt8(const unsigned short* __restrict__ A,
              const unsigned short* __restrict__ B,
              float* __restrict__ Cf,
              const float* __restrict__ bias,
              int M, int N, int K) {
  __shared__ unsigned short sA[2 * 16384];   // 64 KB
  __shared__ unsigned short sB[2 * 16384];   // 64 KB
  const int tid  = threadIdx.x;
  const int lane = tid & 63;
  const int wave = tid >> 6;          // 0..7
  const int wm = wave >> 2;           // 0..1  (M half)
  const int wn = wave & 3;            // 0..3  (N quarter)
  const int q = lane >> 4, r16 = lane & 15;
  const int l8 = lane * 8;
  const int srow = lane & 15;
  const int scol = (lane >> 4) * 8;

  // T1 bijective XCD swizzle (nwg % 8 == 0 for all launches)
  const int gx   = gridDim.x;
  const int nwg  = gx * gridDim.y;
  const int orig = blockIdx.y * gx + blockIdx.x;
  const int swz  = (orig & 7) * (nwg >> 3) + (orig >> 3);
  const int m0 = (swz / gx) * BM8;
  const int n0 = (swz % gx) * BN8;
  const int nt = K >> 6;

  const unsigned short* As = A + (size_t)(m0 + wave * 32 + srow) * K + scol;
  const unsigned short* Bs = B + (size_t)(n0 + wave * 32 + srow) * K + scol;
  unsigned short* sAw = sA + wave * 1024;
  unsigned short* sBw = sB + wave * 1024;

  f32x4 acc[8][4] = {};
  bf16x8 afA[4], afB[4], bvA[4], bvB[4];

  // ---- prologue: tile0 (4 halves) then B1a, A1a, B1b ----
  stage_half2(As, sAw + 0,    K, 0);
  stage_half2(As, sAw + 8192, K, 32);
  stage_half2(Bs, sBw + 0,    K, 0);
  stage_half2(Bs, sBw + 8192, K, 32);
  if (nt > 1) {
    stage_half2(Bs, sBw + 16384,        K, 64);
    stage_half2(As, sAw + 16384,        K, 64);
    stage_half2(Bs, sBw + 16384 + 8192, K, 96);
    WAITV(6);   // drain tile0 (oldest 8), keep tile1's 6 in flight
  } else {
    WAITV(0);
  }
  __builtin_amdgcn_s_barrier();
  // R1 reads for ph1 of g=0
  ld4(sA + (wm * 8 + 0) * 512, l8, afA);
  ld4(sB + (wn * 4)     * 512, l8, bvA);

  for (int g = 0; g < nt; ++g) {
    const int buf  = (g & 1) << 14;     // 0 or 16384
    const int nbuf = 16384 - buf;
    const long long kof = (long long)g * 64;

    // ---------- ph1 ----------
    __builtin_amdgcn_s_barrier();
    ld4(sA + buf + (wm * 8 + 4) * 512, l8, afB);                 // A-a hi (for ph2)
    if (g + 1 < nt) stage_half2(As, sAw + nbuf + 8192, K, kof + 96);   // A(g+1)b
    WAITL(4);
    mfma16(afA, bvA, &acc[0]);

    // ---------- ph2 ----------
    __builtin_amdgcn_s_barrier();
    ld4(sA + buf + 8192 + (wm * 8 + 0) * 512, l8, afA);          // A-b lo (for ph3)
    ld4(sB + buf + 8192 + (wn * 4)     * 512, l8, bvB);          // B-b    (for ph3/4)
    if (g + 2 < nt) stage_half2(Bs, sBw + buf, K, kof + 128);    // B(g+2)a
    WAITL(8);
    mfma16(afB, bvA, &acc[4]);

    // ---------- ph3 ----------
    __builtin_amdgcn_s_barrier();
    ld4(sA + buf + 8192 + (wm * 8 + 4) * 512, l8, afB);          // A-b hi (for ph4)
    if (g + 2 < nt) stage_half2(As, sAw + buf, K, kof + 128);    // A(g+2)a
    WAITL(4);
    mfma16(afA, bvB, &acc[0]);

    // ---------- ph4 ----------
    if (g + 2 < nt)      { WAITV(4); }   // all tile-(g+1) stages retired
    else if (g + 1 < nt) { WAITV(0); }   // tail: drain remaining tile-(g+1)
    __builtin_amdgcn_s_barrier();
    if (g + 1 < nt) {
      ld4(sA + nbuf + (wm * 8 + 0) * 512, l8, afA);              // next-tile A-a lo
      ld4(sB + nbuf + (wn * 4)     * 512, l8, bvA);              // next-tile B-a
    }
    if (g + 2 < nt) stage_half2(Bs, sBw + buf + 8192, K, kof + 160);   // B(g+2)b
    if (g + 1 < nt) { WAITL(8); } else { WAITL(0); }
    mfma16(afB, bvB, &acc[4]);
  }

  // ---------- epilogue ----------
  const int row0 = m0 + wm * 128 + q * 4;
  const int col0 = n0 + wn * 64 + r16;
  float bv[4] = {0.f, 0.f, 0.f, 0.f};
  if (MODE == 0) {
#pragma unroll
    for (int ni = 0; ni < 4; ++ni) bv[ni] = bias[col0 + ni * 16];
  }
#pragma unroll
  for (int mi = 0; mi < 8; ++mi) {
#pragma unroll
    for (int r = 0; r < 4; ++r) {
      const int row = row0 + mi * 16 + r;
      const size_t base = (size_t)row * N + col0;
#pragma unroll
      for (int ni = 0; ni < 4; ++ni) {
        const size_t o = base + (size_t)ni * 16;
        float v = acc[mi][ni][r];
        if (MODE == 0) __builtin_nontemporal_store(v + bv[ni], &Cf[o]);
        else           Cf[o] = v;
      }
    }
  }
}

// ---------- 128x128 B^T GEMM (xs + split-K atomic modes) ----------
constexpr int BM = 128, BN = 128, BK = 64;

template<int MODE>
__global__ void gemm_bt(const unsigned short* __restrict__ A,
                        const unsigned short* __restrict__ B,
                        float* __restrict__ Cf,
                        const float* __restrict__ bias,
                        int M, int N, int K, int kchunk) {
  __shared__ unsigned short sA[BM * BK];   // 16 KB
  __shared__ unsigned short sB[BN * BK];   // 16 KB
  const int tid  = threadIdx.x;
  const int lane = tid & 63;
  const int wave = tid >> 6;
  const int wm = wave >> 1, wn = wave & 1;     // 2x2 waves, each 64x64
  const int q = lane >> 4, r16 = lane & 15;

  const int gx   = gridDim.x;
  const int nwg  = gx * gridDim.y;
  const int orig = blockIdx.y * gx + blockIdx.x;
  const int swz  = (orig & 7) * (nwg >> 3) + (orig >> 3);
  const int m0 = (swz / gx) * BM;
  const int n0 = (swz % gx) * BN;
  const int kb = blockIdx.z * kchunk;

  const int lrow = lane >> 3;        // 0..7 rows within 1KB chunk
  const int lcol = (lane & 7) * 8;   // bf16 elems; 8 elems = 16B

  f32x4 acc[4][4] = {};

  for (int k0 = kb; k0 < kb + kchunk; k0 += BK) {
#pragma unroll
    for (int j = 0; j < 4; ++j) {
      const int c = wave * 4 + j;
      const int row = c * 8 + lrow;
      const unsigned short* ga = A + (size_t)(m0 + row) * K + k0 + lcol;
      __builtin_amdgcn_global_load_lds((gas1_t)(void*)ga, (las3_t)(sA + c * 512), 16, 0, 0);
      const unsigned short* gb = B + (size_t)(n0 + row) * K + k0 + lcol;
      __builtin_amdgcn_global_load_lds((gas1_t)(void*)gb, (las3_t)(sB + c * 512), 16, 0, 0);
    }
    __syncthreads();
#pragma unroll
    for (int kk = 0; kk < BK; kk += 32) {
      bf16x8 af[4], bfv[4];
#pragma unroll
      for (int mi = 0; mi < 4; ++mi)
        af[mi] = *(const bf16x8*)(sA + (size_t)(wm*64 + mi*16 + r16) * BK + kk + q*8);
#pragma unroll
      for (int ni = 0; ni < 4; ++ni)
        bfv[ni] = *(const bf16x8*)(sB + (size_t)(wn*64 + ni*16 + r16) * BK + kk + q*8);
#pragma unroll
      for (int mi = 0; mi < 4; ++mi)
#pragma unroll
        for (int ni = 0; ni < 4; ++ni)
          acc[mi][ni] = __builtin_amdgcn_mfma_f32_16x16x32_bf16(af[mi], bfv[ni], acc[mi][ni], 0, 0, 0);
    }
    __syncthreads();
  }

  const int row0 = m0 + wm*64 + q*4;
  const int col0 = n0 + wn*64 + r16;
  float bv[4] = {0.f, 0.f, 0.f, 0.f};
  if (MODE == 0) {
#pragma unroll
    for (int ni = 0; ni < 4; ++ni) bv[ni] = bias[col0 + ni*16];
  }
#pragma unroll
  for (int mi = 0; mi < 4; ++mi) {
#pragma unroll
    for (int r = 0; r < 4; ++r) {
      const int row = row0 + mi*16 + r;
      const size_t base = (size_t)row * N + col0;
#pragma unroll
      for (int ni = 0; ni < 4; ++ni) {
        const size_t o = base + (size_t)ni * 16;
        float v = acc[mi][ni][r];
        if (MODE == 0)      __builtin_nontemporal_store(v + bv[ni], &Cf[o]);
        else if (MODE == 2) Cf[o] = v;
        else                atomicAdd(&Cf[o], v);
      }
    }
  }
}

// ---------- fp32 -> bf16 bulk convert (4 elems/thread); NT==1 streams the fp32 read ----------
template<int NT>
__global__ void cvt_f32_bf16(const float* __restrict__ in, unsigned short* __restrict__ out, long long n) {
  long long i = ((long long)blockIdx.x * 256 + threadIdx.x) * 4;
  if (i >= n) return;
  f32x4 v;
  if (NT) v = __builtin_nontemporal_load((const f32x4*)(in + i));
  else    v = *(const f32x4*)(in + i);
  u16x4 o;
  o.x = f2bf(v.x); o.y = f2bf(v.y); o.z = f2bf(v.z); o.w = f2bf(v.w);
  *(u16x4*)(out + i) = o;
}

// ---------- gather sampled tokens from bf16 x: ab[blk][:] = xb[b][idx][:] ----------
__global__ void gather_rows(const unsigned short* __restrict__ xb, const int* __restrict__ idx,
                            unsigned short* __restrict__ out) {
  const int blk = blockIdx.x;            // 0..8191 = b*2048+n
  const int b = blk >> 11, n = blk & 2047;
  const int row = idx[b * NSAMP + n];
  const unsigned short* src = xb + ((size_t)b * Lc + row) * Dc;
  unsigned short* dst = out + (size_t)blk * Dc;
  const int c = threadIdx.x * 4;
  *(u16x4*)(dst + c) = *(const u16x4*)(src + c);
}

// ---------- diagonal residual: c[i] = d_ii - bf16(d_ii) ----------
__global__ void diag_resid(const float* __restrict__ dc, float* __restrict__ cvec) {
  const int i = blockIdx.x * 256 + threadIdx.x;
  if (i >= Dc) return;
  const float v = dc[(size_t)i * Dc + i];
  cvec[i] = v - bf2f(f2bf(v));
}

// ---------- fp32 transpose -> bf16 (64x64 LDS tiles): outT[c][r] = bf16(in[r][c]) ----------
__global__ void transpose_bf16(const float* __restrict__ in, unsigned short* __restrict__ outT,
                               int R, int C) {
  __shared__ float tile[64][65];
  const int r0 = blockIdx.y * 64, c0 = blockIdx.x * 64;
  const int t = threadIdx.x;
  const int c = t & 63, r4 = t >> 6;
#pragma unroll
  for (int j = 0; j < 16; ++j) {
    const int r = j * 4 + r4;
    tile[r][c] = in[(size_t)(r0 + r) * C + c0 + c];
  }
  __syncthreads();
  const int i = t >> 2, p = t & 3;
  unsigned short* dst = outT + (size_t)(c0 + i) * R + r0 + p * 16;
#pragma unroll
  for (int j = 0; j < 16; j += 4) {
    u16x4 v;
    v.x = f2bf(tile[p*16 + j + 0][i]);
    v.y = f2bf(tile[p*16 + j + 1][i]);
    v.z = f2bf(tile[p*16 + j + 2][i]);
    v.w = f2bf(tile[p*16 + j + 3][i]);
    *(u16x4*)(dst + j) = v;
  }
}

// ---------- fused xs pass: diag correction; per-row s1=Σx²,s2=Σx⁴; per-col Σx²; bf16 transpose ----------
__global__ void xs_stats_transpose(const float* __restrict__ xs, const unsigned short* __restrict__ ab,
                                   const float* __restrict__ cvec,
                                   unsigned short* __restrict__ xsT,
                                   float* __restrict__ m2sum, float* __restrict__ s1g,
                                   float* __restrict__ s2g) {
  __shared__ float tile[64][65];
  const int n0 = blockIdx.x * 64;   // sample rows (8192)
  const int i0 = blockIdx.y * 64;   // feature cols (1024)
  const int t = threadIdx.x;
  const int c = t & 63, r4 = t >> 6;
  const float ccol = cvec[i0 + c];
#pragma unroll
  for (int j = 0; j < 16; ++j) {
    const int r = j * 4 + r4;
    const size_t o = (size_t)(n0 + r) * Dc + i0 + c;
    tile[r][c] = xs[o] + bf2f(ab[o]) * ccol;   // exact-diag correction
  }
  __syncthreads();
  if (t < 64) {
    float s1 = 0.f, s2 = 0.f;
#pragma unroll
    for (int cc = 0; cc < 64; ++cc) { float v = tile[t][cc]; float v2 = v*v; s1 += v2; s2 += v2*v2; }
    atomicAdd(&s1g[n0 + t], s1);
    atomicAdd(&s2g[n0 + t], s2);
  } else if (t < 128) {
    const int col = t - 64;
    float cs = 0.f;
#pragma unroll
    for (int rr = 0; rr < 64; ++rr) { float v = tile[rr][col]; cs += v*v; }
    atomicAdd(&m2sum[i0 + col], cs);
  }
  const int i = t >> 2, p = t & 3;
  unsigned short* dst = xsT + (size_t)(i0 + i) * NSEL + n0 + p * 16;
#pragma unroll
  for (int j = 0; j < 16; j += 4) {
    u16x4 v;
    v.x = f2bf(tile[p*16 + j + 0][i]);
    v.y = f2bf(tile[p*16 + j + 1][i]);
    v.z = f2bf(tile[p*16 + j + 2][i]);
    v.w = f2bf(tile[p*16 + j + 3][i]);
    *(u16x4*)(dst + j) = v;
  }
}

// ---------- grad writeout: off-diag 0.5*G/N, diag 0.5*(m2-1) ----------
__global__ void grad_write(const float* __restrict__ G, const float* __restrict__ m2sum,
                           float* __restrict__ out) {
  const int i = blockIdx.x * 256 + threadIdx.x;   // 0..1048575
  const int r = i >> 10, c = i & 1023;
  float g = G[i] * (0.5f / (float)NSEL);
  if (r == c) g = 0.5f * (m2sum[r] * (1.0f / (float)NSEL) - 1.0f);
  __builtin_nontemporal_store(g, &out[i]);
}

// ---------- losses: corr=(Σs1²−Σs2)/denom, white=(Σs2−2Σs1+N·d)/denom ----------
__global__ void finalize_losses(const float* __restrict__ s1g, const float* __restrict__ s2g,
                                float* __restrict__ out2) {
  __shared__ double sa[256], sb[256], sc[256];
  double a = 0, b = 0, c = 0;
  for (int n = threadIdx.x; n < NSEL; n += 256) {
    double s1 = s1g[n], s2 = s2g[n];
    a += s1 * s1; b += s2; c += s1;
  }
  const int t = threadIdx.x;
  sa[t] = a; sb[t] = b; sc[t] = c;
  __syncthreads();
  for (int s = 128; s > 0; s >>= 1) {
    if (t < s) { sa[t] += sa[t+s]; sb[t] += sb[t+s]; sc[t] += sc[t+s]; }
    __syncthreads();
  }
  if (t == 0) {
    const double denom = (double)NSEL * (double)Dc * (double)Dc;
    const double cnt   = (double)NSEL * (double)Dc;
    out2[0] = (float)((sa[0] - sb[0]) / denom);
    out2[1] = (float)((sb[0] - 2.0 * sc[0] + cnt) / denom);
  }
}

extern "C" void kernel_launch(void* const* d_in, const int* in_sizes, int n_in,
                              void* d_out, int out_size, void* d_ws, size_t ws_size,
                              hipStream_t stream) {
  const float* x      = (const float*)d_in[0];
  const float* W      = (const float*)d_in[1];
  const float* bias   = (const float*)d_in[2];
  const float* decorr = (const float*)d_in[3];
  const int*   sidx   = (const int*)d_in[4];
  float* out = (float*)d_out;

  // workspace layout (bytes)
  char* w = (char*)d_ws;
  constexpr size_t SZ_XB  = (size_t)ROWS * Dc * 2;       // x bf16            64 MB
  constexpr size_t SZ_AB  = (size_t)NSEL * Dc * 2;       // gathered sel bf16 16 MB
  constexpr size_t SZ_DT  = (size_t)Dc * Dc * 2;         // decorr^T bf16      2 MB
  constexpr size_t SZ_WB  = (size_t)Dc * Dc * 2;         // W bf16             2 MB
  constexpr size_t SZ_MB  = (size_t)Dc * Dc * 2;         // M bf16             2 MB
  constexpr size_t SZ_XS  = (size_t)NSEL * Dc * 4;       // xs fp32           32 MB
  constexpr size_t SZ_XST = (size_t)Dc * NSEL * 2;       // xs^T bf16         16 MB
  constexpr size_t SZ_MF  = (size_t)Dc * Dc * 4;         // M fp32 acc         4 MB (zeroed)
  constexpr size_t SZ_GB  = (size_t)Dc * Dc * 4;         // G fp32 acc         4 MB (zeroed)
  constexpr size_t SZ_M2  = (size_t)Dc * 4;
  constexpr size_t SZ_S1  = (size_t)NSEL * 4;
  constexpr size_t SZ_S2  = (size_t)NSEL * 4;
  constexpr size_t SZ_CV  = (size_t)Dc * 4;

  size_t off = 0;
  unsigned short* xb  = (unsigned short*)(w + off); off += SZ_XB;
  unsigned short* ab  = (unsigned short*)(w + off); off += SZ_AB;
  unsigned short* dT  = (unsigned short*)(w + off); off += SZ_DT;
  unsigned short* wb  = (unsigned short*)(w + off); off += SZ_WB;
  unsigned short* mb  = (unsigned short*)(w + off); off += SZ_MB;
  float*          xsf = (float*)(w + off);          off += SZ_XS;
  unsigned short* xsT = (unsigned short*)(w + off); off += SZ_XST;
  float*          cv  = (float*)(w + off);          off += SZ_CV;
  char*           zbase = w + off;                   // zeroed region
  float*          Mf  = (float*)(w + off);          off += SZ_MF;
  float*          Gb  = (float*)(w + off);          off += SZ_GB;
  float*          m2s = (float*)(w + off);          off += SZ_M2;
  float*          s1g = (float*)(w + off);          off += SZ_S1;
  float*          s2g = (float*)(w + off);          off += SZ_S2;
  const size_t zbytes = SZ_MF + SZ_GB + SZ_M2 + SZ_S1 + SZ_S2;

  (void)hipMemsetAsync(zbase, 0, zbytes, stream);

  // prep
  cvt_f32_bf16<1><<<(int)(Y_ELEMS / 1024), 256, 0, stream>>>(x, xb, Y_ELEMS);
  cvt_f32_bf16<0><<<Dc*Dc / 1024, 256, 0, stream>>>(W, wb, (long long)Dc*Dc);
  diag_resid<<<4, 256, 0, stream>>>(decorr, cv);
  transpose_bf16<<<dim3(Dc/64, Dc/64), 256, 0, stream>>>(decorr, dT, Dc, Dc);
  gather_rows<<<NSEL, 256, 0, stream>>>(xb, sidx, ab);

  // M = W @ decorr : split-K=8 atomic fp32 (512 blocks), then cvt to bf16
  gemm_bt<3><<<dim3(Dc/BN, Dc/BM, 8), 256, 0, stream>>>(wb, dT, Mf, nullptr, Dc, Dc, Dc, Dc/8);
  cvt_f32_bf16<0><<<Dc*Dc / 1024, 256, 0, stream>>>(Mf, mb, (long long)Dc*Dc);

  // y = x @ M^T + bias (nt stores) : 256^2 pipelined 4-phase
  gemm_bt8<0><<<dim3(Dc/BN8, ROWS/BM8), 512, 0, stream>>>(xb, mb, out, bias, ROWS, Dc, Dc);

  // xs = sel @ decorr^T : 128^2 (512 blocks, full GPU)
  gemm_bt<2><<<dim3(Dc/BN, NSEL/BM, 1), 256, 0, stream>>>(ab, dT, xsf, nullptr, NSEL, Dc, Dc, Dc);

  // stats + correction + transpose
  xs_stats_transpose<<<dim3(NSEL/64, Dc/64), 256, 0, stream>>>(xsf, ab, cv, xsT, m2s, s1g, s2g);

  // G = xs^T xs : split-K=16 atomic (1024 blocks)
  gemm_bt<3><<<dim3(Dc/BN, Dc/BM, 16), 256, 0, stream>>>(xsT, xsT, Gb, nullptr, Dc, Dc, NSEL, NSEL/16);

  // outputs
  grad_write<<<Dc*Dc / 256, 256, 0, stream>>>(Gb, m2s, out + GRAD_OFF);
  finalize_losses<<<1, 256, 0, stream>>>(s1g, s2g, out + LOSS_OFF);
}

// Round 4
// 422.477 us; speedup vs baseline: 1.1927x; 1.1514x over previous
//
#include <hip/hip_runtime.h>
#include <cstdint>
#include <cstddef>

// ---------- types & helpers ----------
typedef __bf16 bf16x8 __attribute__((ext_vector_type(8)));
typedef float  f32x4  __attribute__((ext_vector_type(4)));
typedef unsigned short u16x4 __attribute__((ext_vector_type(4)));

typedef __attribute__((address_space(1))) void* gas1_t;
typedef __attribute__((address_space(3))) void* las3_t;

__device__ __forceinline__ unsigned short f2bf(float f) {
  union { float f; unsigned u; } v; v.f = f;
  unsigned r = v.u + 0x7fffu + ((v.u >> 16) & 1u);   // RNE
  return (unsigned short)(r >> 16);
}
__device__ __forceinline__ float bf2f(unsigned short h) {
  union { unsigned u; float f; } v; v.u = ((unsigned)h) << 16;
  return v.f;
}

// ---------- problem constants ----------
constexpr int Bc = 4, Lc = 8192, Dc = 1024, NSAMP = 2048;
constexpr int ROWS = Bc * Lc;        // 32768
constexpr int NSEL = Bc * NSAMP;     // 8192
constexpr long long Y_ELEMS = (long long)ROWS * Dc;          // 33554432
constexpr long long GRAD_OFF = Y_ELEMS;                      // grad after y
constexpr long long LOSS_OFF = GRAD_OFF + (long long)Dc*Dc;  // 34603008

// ---------- 128x128 B^T GEMM: C[m][n] = sum_k A[m][k]*B[n][k], bf16 in ----------
// MODE 0: nt-store Cf = acc + bias[col]          (y)
// MODE 5: bf16 store ((ushort*)Cf)[o] = bf16(acc) (M = W@decorr, direct bf16)
// MODE 6: triangular tile decode + atomicAdd      (G = xsT xsT^T, symmetric)
constexpr int BM = 128, BN = 128, BK = 64;

template<int MODE>
__global__ void gemm_bt(const unsigned short* __restrict__ A,
                        const unsigned short* __restrict__ B,
                        float* __restrict__ Cf,
                        const float* __restrict__ bias,
                        int M, int N, int K, int kchunk) {
  __shared__ unsigned short sA[BM * BK];   // 16 KB
  __shared__ unsigned short sB[BN * BK];   // 16 KB
  const int tid  = threadIdx.x;
  const int lane = tid & 63;
  const int wave = tid >> 6;
  const int wm = wave >> 1, wn = wave & 1;     // 2x2 waves, each 64x64
  const int q = lane >> 4, r16 = lane & 15;

  int m0, n0;
  if constexpr (MODE == 6) {
    // upper-triangle tile decode: blockIdx.x in [0,36) -> (ti, tj), ti <= tj
    int t = blockIdx.x, ti = 0;
    while (t >= 8 - ti) { t -= 8 - ti; ++ti; }
    m0 = ti * BM; n0 = (ti + t) * BN;
  } else {
    // T1 bijective XCD swizzle (nwg % 8 == 0 for all launches using this path)
    const int gx   = gridDim.x;
    const int nwg  = gx * gridDim.y;
    const int orig = blockIdx.y * gx + blockIdx.x;
    const int swz  = (orig & 7) * (nwg >> 3) + (orig >> 3);
    m0 = (swz / gx) * BM;
    n0 = (swz % gx) * BN;
  }
  const int kb = blockIdx.z * kchunk;

  const int lrow = lane >> 3;        // 0..7 rows within 1KB chunk
  const int lcol = (lane & 7) * 8;   // bf16 elems; 8 elems = 16B

  f32x4 acc[4][4] = {};

  for (int k0 = kb; k0 < kb + kchunk; k0 += BK) {
#pragma unroll
    for (int j = 0; j < 4; ++j) {
      const int c = wave * 4 + j;
      const int row = c * 8 + lrow;
      const unsigned short* ga = A + (size_t)(m0 + row) * K + k0 + lcol;
      __builtin_amdgcn_global_load_lds((gas1_t)(void*)ga, (las3_t)(sA + c * 512), 16, 0, 0);
      const unsigned short* gb = B + (size_t)(n0 + row) * K + k0 + lcol;
      __builtin_amdgcn_global_load_lds((gas1_t)(void*)gb, (las3_t)(sB + c * 512), 16, 0, 0);
    }
    __syncthreads();
#pragma unroll
    for (int kk = 0; kk < BK; kk += 32) {
      bf16x8 af[4], bfv[4];
#pragma unroll
      for (int mi = 0; mi < 4; ++mi)
        af[mi] = *(const bf16x8*)(sA + (size_t)(wm*64 + mi*16 + r16) * BK + kk + q*8);
#pragma unroll
      for (int ni = 0; ni < 4; ++ni)
        bfv[ni] = *(const bf16x8*)(sB + (size_t)(wn*64 + ni*16 + r16) * BK + kk + q*8);
#pragma unroll
      for (int mi = 0; mi < 4; ++mi)
#pragma unroll
        for (int ni = 0; ni < 4; ++ni)
          acc[mi][ni] = __builtin_amdgcn_mfma_f32_16x16x32_bf16(af[mi], bfv[ni], acc[mi][ni], 0, 0, 0);
    }
    __syncthreads();
  }

  // epilogue: lane holds C[row = q*4+r][col = r16] per 16x16 tile (m89/m91 layout)
  // ni innermost: the 2 store instrs covering one 128B line issue back-to-back.
  const int row0 = m0 + wm*64 + q*4;
  const int col0 = n0 + wn*64 + r16;
  float bv[4] = {0.f, 0.f, 0.f, 0.f};
  if (MODE == 0) {
#pragma unroll
    for (int ni = 0; ni < 4; ++ni) bv[ni] = bias[col0 + ni*16];
  }
#pragma unroll
  for (int mi = 0; mi < 4; ++mi) {
#pragma unroll
    for (int r = 0; r < 4; ++r) {
      const int row = row0 + mi*16 + r;
      const size_t base = (size_t)row * N + col0;
#pragma unroll
      for (int ni = 0; ni < 4; ++ni) {
        const size_t o = base + (size_t)ni * 16;
        float v = acc[mi][ni][r];
        if (MODE == 0)      __builtin_nontemporal_store(v + bv[ni], &Cf[o]);
        else if (MODE == 5) ((unsigned short*)Cf)[o] = f2bf(v);
        else                atomicAdd(&Cf[o], v);
      }
    }
  }
}

// ---------- fused xs pass: GEMM (ab @ dT^T) + diag correction + stats + bf16 transpose ----
// One kernel replaces {xs-GEMM -> 32MB fp32 -> stats kernel}. Epilogue:
//   v = acc + ab[row][col]*cvec[col]  (exact-diag correction, in-register)
//   bf16 tile -> padded LDS -> s1/s2 per row, m2 per col, coalesced xsT write.
// Stats computed on bf16-rounded values (RNE unbiased; loss err ~1e-4 << tol).
__global__ __launch_bounds__(256)
void xs_gemm_fused(const unsigned short* __restrict__ A,   // ab [NSEL][Dc]
                   const unsigned short* __restrict__ B,   // dT [Dc][Dc]
                   const float* __restrict__ cvec,
                   unsigned short* __restrict__ xsT,       // [Dc][NSEL]
                   float* __restrict__ m2sum, float* __restrict__ s1g,
                   float* __restrict__ s2g,
                   int M, int N, int K) {
  __shared__ __attribute__((aligned(16))) unsigned short shm[128 * 136];  // 34816 B
  unsigned short* sA = shm;            // staging A [128*64] = 16 KB
  unsigned short* sB = shm + 8192;     // staging B [128*64] = 16 KB
  const int tid  = threadIdx.x;
  const int lane = tid & 63;
  const int wave = tid >> 6;
  const int wm = wave >> 1, wn = wave & 1;
  const int q = lane >> 4, r16 = lane & 15;

  const int gx   = gridDim.x;
  const int nwg  = gx * gridDim.y;
  const int orig = blockIdx.y * gx + blockIdx.x;
  const int swz  = (orig & 7) * (nwg >> 3) + (orig >> 3);
  const int m0 = (swz / gx) * BM;   // sample tile base
  const int n0 = (swz % gx) * BN;   // feature tile base

  const int lrow = lane >> 3;
  const int lcol = (lane & 7) * 8;

  f32x4 acc[4][4] = {};

  for (int k0 = 0; k0 < K; k0 += BK) {
#pragma unroll
    for (int j = 0; j < 4; ++j) {
      const int c = wave * 4 + j;
      const int row = c * 8 + lrow;
      const unsigned short* ga = A + (size_t)(m0 + row) * K + k0 + lcol;
      __builtin_amdgcn_global_load_lds((gas1_t)(void*)ga, (las3_t)(sA + c * 512), 16, 0, 0);
      const unsigned short* gb = B + (size_t)(n0 + row) * K + k0 + lcol;
      __builtin_amdgcn_global_load_lds((gas1_t)(void*)gb, (las3_t)(sB + c * 512), 16, 0, 0);
    }
    __syncthreads();
#pragma unroll
    for (int kk = 0; kk < BK; kk += 32) {
      bf16x8 af[4], bfv[4];
#pragma unroll
      for (int mi = 0; mi < 4; ++mi)
        af[mi] = *(const bf16x8*)(sA + (size_t)(wm*64 + mi*16 + r16) * BK + kk + q*8);
#pragma unroll
      for (int ni = 0; ni < 4; ++ni)
        bfv[ni] = *(const bf16x8*)(sB + (size_t)(wn*64 + ni*16 + r16) * BK + kk + q*8);
#pragma unroll
      for (int mi = 0; mi < 4; ++mi)
#pragma unroll
        for (int ni = 0; ni < 4; ++ni)
          acc[mi][ni] = __builtin_amdgcn_mfma_f32_16x16x32_bf16(af[mi], bfv[ni], acc[mi][ni], 0, 0, 0);
    }
    __syncthreads();
  }

  // ---- epilogue: correction + bf16 tile into LDS (pitch 136 kills stride-256B conflicts)
  const int lr0 = wm*64 + q*4;          // local sample row base
  const int lc0 = wn*64 + r16;          // local feature col base
  float cvl[4];
#pragma unroll
  for (int ni = 0; ni < 4; ++ni) cvl[ni] = cvec[n0 + lc0 + ni*16];
#pragma unroll
  for (int mi = 0; mi < 4; ++mi) {
#pragma unroll
    for (int r = 0; r < 4; ++r) {
      const int lr = lr0 + mi*16 + r;
      const size_t arow = (size_t)(m0 + lr) * K;
#pragma unroll
      for (int ni = 0; ni < 4; ++ni) {
        const int lc = lc0 + ni*16;
        float v = acc[mi][ni][r] + bf2f(A[arow + n0 + lc]) * cvl[ni];
        shm[lr * 136 + lc] = f2bf(v);
      }
    }
  }
  __syncthreads();

  // ---- stats from LDS: waves 0-1 -> per-row s1,s2; waves 2-3 -> per-col m2
  if (tid < 128) {
    float s1 = 0.f, s2 = 0.f;
#pragma unroll 8
    for (int c = 0; c < 128; ++c) {
      float v = bf2f(shm[tid * 136 + c]); float v2 = v * v;
      s1 += v2; s2 += v2 * v2;
    }
    atomicAdd(&s1g[m0 + tid], s1);
    atomicAdd(&s2g[m0 + tid], s2);
  } else {
    const int col = tid - 128;
    float cs = 0.f;
#pragma unroll 8
    for (int r = 0; r < 128; ++r) {
      float v = bf2f(shm[r * 136 + col]); cs += v * v;
    }
    atomicAdd(&m2sum[n0 + col], cs);
  }

  // ---- transposed coalesced write: feature fi = tid>>1, sample half = tid&1
  const int fi = tid >> 1, hh = tid & 1;
  unsigned short* dst = xsT + (size_t)(n0 + fi) * M + m0 + hh * 64;
#pragma unroll
  for (int j = 0; j < 64; j += 4) {
    u16x4 v;
    v.x = shm[(hh*64 + j + 0) * 136 + fi];
    v.y = shm[(hh*64 + j + 1) * 136 + fi];
    v.z = shm[(hh*64 + j + 2) * 136 + fi];
    v.w = shm[(hh*64 + j + 3) * 136 + fi];
    *(u16x4*)(dst + j) = v;
  }
}

// ---------- fp32 -> bf16 bulk convert (4 elems/thread); NT==1 streams the fp32 read ----------
template<int NT>
__global__ void cvt_f32_bf16(const float* __restrict__ in, unsigned short* __restrict__ out, long long n) {
  long long i = ((long long)blockIdx.x * 256 + threadIdx.x) * 4;
  if (i >= n) return;
  f32x4 v;
  if (NT) v = __builtin_nontemporal_load((const f32x4*)(in + i));
  else    v = *(const f32x4*)(in + i);
  u16x4 o;
  o.x = f2bf(v.x); o.y = f2bf(v.y); o.z = f2bf(v.z); o.w = f2bf(v.w);
  *(u16x4*)(out + i) = o;
}

// ---------- gather sampled tokens from bf16 x: ab[blk][:] = xb[b][idx][:] ----------
__global__ void gather_rows(const unsigned short* __restrict__ xb, const int* __restrict__ idx,
                            unsigned short* __restrict__ out) {
  const int blk = blockIdx.x;            // 0..8191 = b*2048+n
  const int b = blk >> 11, n = blk & 2047;
  const int row = idx[b * NSAMP + n];
  const unsigned short* src = xb + ((size_t)b * Lc + row) * Dc;
  unsigned short* dst = out + (size_t)blk * Dc;
  const int c = threadIdx.x * 4;
  *(u16x4*)(dst + c) = *(const u16x4*)(src + c);
}

// ---------- fused prep: wb = bf16(W); dT = bf16(decorr^T); cv = diag residual ----------
__global__ void prep_wdt(const float* __restrict__ W, const float* __restrict__ dc,
                         unsigned short* __restrict__ wb, unsigned short* __restrict__ dT,
                         float* __restrict__ cvec) {
  __shared__ float tile[64][65];
  const int r0 = blockIdx.y * 64, c0 = blockIdx.x * 64;
  const int t = threadIdx.x;
  const int c = t & 63, r4 = t >> 6;
#pragma unroll
  for (int j = 0; j < 16; ++j) {
    const int r = j * 4 + r4;
    const size_t o = (size_t)(r0 + r) * Dc + c0 + c;
    wb[o] = f2bf(W[o]);
    tile[r][c] = dc[o];
  }
  __syncthreads();
  if (blockIdx.x == blockIdx.y && t < 64) {
    const float v = tile[t][t];
    cvec[c0 + t] = v - bf2f(f2bf(v));
  }
  const int i = t >> 2, p = t & 3;
  unsigned short* dst = dT + (size_t)(c0 + i) * Dc + r0 + p * 16;
#pragma unroll
  for (int j = 0; j < 16; j += 4) {
    u16x4 v;
    v.x = f2bf(tile[p*16 + j + 0][i]);
    v.y = f2bf(tile[p*16 + j + 1][i]);
    v.z = f2bf(tile[p*16 + j + 2][i]);
    v.w = f2bf(tile[p*16 + j + 3][i]);
    *(u16x4*)(dst + j) = v;
  }
}

// ---------- grad writeout: off-diag 0.5*G/N (triangle-mirrored), diag 0.5*(m2-1) ----------
__global__ void grad_write(const float* __restrict__ G, const float* __restrict__ m2sum,
                           float* __restrict__ out) {
  const int i = blockIdx.x * 256 + threadIdx.x;   // 0..1048575
  const int r = i >> 10, c = i & 1023;
  int rr = r, cc = c;
  if ((r >> 7) > (c >> 7)) { rr = c; cc = r; }    // only upper-triangle tiles computed
  float g = G[rr * 1024 + cc] * (0.5f / (float)NSEL);
  if (r == c) g = 0.5f * (m2sum[r] * (1.0f / (float)NSEL) - 1.0f);
  __builtin_nontemporal_store(g, &out[i]);
}

// ---------- losses: corr=(Σs1²−Σs2)/denom, white=(Σs2−2Σs1+N·d)/denom ----------
__global__ void finalize_losses(const float* __restrict__ s1g, const float* __restrict__ s2g,
                                float* __restrict__ out2) {
  __shared__ double sa[256], sb[256], sc[256];
  double a = 0, b = 0, c = 0;
  for (int n = threadIdx.x; n < NSEL; n += 256) {
    double s1 = s1g[n], s2 = s2g[n];
    a += s1 * s1; b += s2; c += s1;
  }
  const int t = threadIdx.x;
  sa[t] = a; sb[t] = b; sc[t] = c;
  __syncthreads();
  for (int s = 128; s > 0; s >>= 1) {
    if (t < s) { sa[t] += sa[t+s]; sb[t] += sb[t+s]; sc[t] += sc[t+s]; }
    __syncthreads();
  }
  if (t == 0) {
    const double denom = (double)NSEL * (double)Dc * (double)Dc;
    const double cnt   = (double)NSEL * (double)Dc;
    out2[0] = (float)((sa[0] - sb[0]) / denom);
    out2[1] = (float)((sb[0] - 2.0 * sc[0] + cnt) / denom);
  }
}

extern "C" void kernel_launch(void* const* d_in, const int* in_sizes, int n_in,
                              void* d_out, int out_size, void* d_ws, size_t ws_size,
                              hipStream_t stream) {
  const float* x      = (const float*)d_in[0];
  const float* W      = (const float*)d_in[1];
  const float* bias   = (const float*)d_in[2];
  const float* decorr = (const float*)d_in[3];
  const int*   sidx   = (const int*)d_in[4];
  float* out = (float*)d_out;

  // workspace layout (bytes)
  char* w = (char*)d_ws;
  constexpr size_t SZ_XB  = (size_t)ROWS * Dc * 2;       // x bf16            64 MB
  constexpr size_t SZ_AB  = (size_t)NSEL * Dc * 2;       // gathered sel bf16 16 MB
  constexpr size_t SZ_DT  = (size_t)Dc * Dc * 2;         // decorr^T bf16      2 MB
  constexpr size_t SZ_WB  = (size_t)Dc * Dc * 2;         // W bf16             2 MB
  constexpr size_t SZ_MB  = (size_t)Dc * Dc * 2;         // M bf16             2 MB
  constexpr size_t SZ_XST = (size_t)Dc * NSEL * 2;       // xs^T bf16         16 MB
  constexpr size_t SZ_CV  = (size_t)Dc * 4;
  constexpr size_t SZ_GB  = (size_t)Dc * Dc * 4;         // G fp32 acc         4 MB (zeroed)
  constexpr size_t SZ_M2  = (size_t)Dc * 4;
  constexpr size_t SZ_S1  = (size_t)NSEL * 4;
  constexpr size_t SZ_S2  = (size_t)NSEL * 4;

  size_t off = 0;
  unsigned short* xb  = (unsigned short*)(w + off); off += SZ_XB;
  unsigned short* ab  = (unsigned short*)(w + off); off += SZ_AB;
  unsigned short* dT  = (unsigned short*)(w + off); off += SZ_DT;
  unsigned short* wb  = (unsigned short*)(w + off); off += SZ_WB;
  unsigned short* mb  = (unsigned short*)(w + off); off += SZ_MB;
  unsigned short* xsT = (unsigned short*)(w + off); off += SZ_XST;
  float*          cv  = (float*)(w + off);          off += SZ_CV;
  char*           zbase = w + off;                   // zeroed region
  float*          Gb  = (float*)(w + off);          off += SZ_GB;
  float*          m2s = (float*)(w + off);          off += SZ_M2;
  float*          s1g = (float*)(w + off);          off += SZ_S1;
  float*          s2g = (float*)(w + off);          off += SZ_S2;
  const size_t zbytes = SZ_GB + SZ_M2 + SZ_S1 + SZ_S2;

  (void)hipMemsetAsync(zbase, 0, zbytes, stream);

  // prep
  cvt_f32_bf16<1><<<(int)(Y_ELEMS / 1024), 256, 0, stream>>>(x, xb, Y_ELEMS);
  prep_wdt<<<dim3(16, 16), 256, 0, stream>>>(W, decorr, wb, dT, cv);
  gather_rows<<<NSEL, 256, 0, stream>>>(xb, sidx, ab);

  // M = W @ decorr : direct bf16 epilogue, no split-K, no atomics, no cvt
  gemm_bt<5><<<dim3(Dc/BN, Dc/BM, 1), 256, 0, stream>>>(wb, dT, (float*)mb, nullptr, Dc, Dc, Dc, Dc);

  // y = x @ M^T + bias (nt stores)
  gemm_bt<0><<<dim3(Dc/BN, ROWS/BM, 1), 256, 0, stream>>>(xb, mb, out, bias, ROWS, Dc, Dc, Dc);

  // xs fused: GEMM + diag correction + stats + bf16 transpose (no fp32 xs buffer)
  xs_gemm_fused<<<dim3(Dc/BN, NSEL/BM), 256, 0, stream>>>(ab, dT, cv, xsT, m2s, s1g, s2g,
                                                          NSEL, Dc, Dc);

  // G = xs^T xs : symmetric -> 36 upper-triangle tiles, split-K=8 atomic
  gemm_bt<6><<<dim3(36, 1, 8), 256, 0, stream>>>(xsT, xsT, Gb, nullptr, Dc, Dc, NSEL, NSEL/8);

  // outputs
  grad_write<<<Dc*Dc / 256, 256, 0, stream>>>(Gb, m2s, out + GRAD_OFF);
  finalize_losses<<<1, 256, 0, stream>>>(s1g, s2g, out + LOSS_OFF);
}